// Round 19
// baseline (1109.010 us; speedup 1.0000x reference)
//
#include <hip/hip_runtime.h>

#define F_IN 165
#define KP_PROJ 168
constexpr float NEG_SLOPE = 0.2f;

// lrelu(z) = max(z, 0.2z) -- 2 VALU inst vs 3 for cmp/cndmask form.
__device__ __forceinline__ float lrelu(float z) { return fmaxf(z, NEG_SLOPE * z); }

// ---- weight transposes + va vectors + fused degree count --------------------
__global__ void k_trans(const float* __restrict__ pw, const float* __restrict__ w2,
                        const float* __restrict__ w1, const float* __restrict__ as1w,
                        const float* __restrict__ ad1w,
                        float* __restrict__ t0, float* __restrict__ t2,
                        float* __restrict__ va,
                        const int* __restrict__ ei, int E, int* __restrict__ deg) {
    int i = blockIdx.x * 256 + threadIdx.x;
    const int n0 = 64 * KP_PROJ, n2 = 64 * 256;
    if (i < n0) {
        int c = i / KP_PROJ, r = i - c * KP_PROJ;
        t0[i] = (r < F_IN) ? pw[r * 64 + c] : 0.f;
    } else if (i < n0 + n2) {
        int j = i - n0; int c = j >> 8, r = j & 255;
        t2[j] = w2[r * 64 + c];
    } else if (i < n0 + n2 + 512) {
        int j = i - n0 - n2;          // 0..511
        int i2 = j >> 6;              // 0..7 = plane*4 + h
        int plane = i2 >> 2, h = i2 & 3, k = j & 63;
        const float* att = plane ? ad1w : as1w;
        float acc = 0.f;
        for (int c = 0; c < 64; ++c)
            acc = fmaf(w1[k * 256 + h * 64 + c], att[h * 64 + c], acc);
        va[j] = acc;
    }
    int z = i - (n0 + n2 + 512);
    if (z >= 0 && z < E) atomicAdd(&deg[ei[E + z]], 1);
}

// ---- h0 = relu(x @ W + b) + fused as1/ad1 via single-wave LDS transpose -----
__global__ void k_proj(const float* __restrict__ x, const float* __restrict__ Wt,
                       const float* __restrict__ b, const float* __restrict__ va,
                       float* __restrict__ h0, float* __restrict__ as_,
                       float* __restrict__ ad_, int N) {
    __shared__ float xs[32][KP_PROJ];
    __shared__ float vas[8][65];
    __shared__ float hrow[4][64];
    int base = blockIdx.x * 32;
    int t = threadIdx.x;
    for (int idx = t; idx < 512; idx += 256)
        vas[idx >> 6][idx & 63] = va[idx];
    for (int idx = t; idx < 32 * KP_PROJ; idx += 256) {
        int nl = idx / KP_PROJ, k = idx - nl * KP_PROJ;
        int node = base + nl;
        xs[nl][k] = (node < N && k < F_IN) ? x[(size_t)node * F_IN + k] : 0.f;
    }
    __syncthreads();
    int g = t >> 6, col = t & 63;
    float acc[8];
    float bb = b[col];
#pragma unroll
    for (int m = 0; m < 8; ++m) acc[m] = bb;
    const float* wrow = Wt + col * KP_PROJ;
    for (int k4 = 0; k4 < KP_PROJ / 4; ++k4) {
        float4 wv = *(const float4*)(wrow + k4 * 4);
#pragma unroll
        for (int m = 0; m < 8; ++m) {
            float4 av = *(const float4*)&xs[g * 8 + m][k4 * 4];
            acc[m] = fmaf(av.x, wv.x, acc[m]);
            acc[m] = fmaf(av.y, wv.y, acc[m]);
            acc[m] = fmaf(av.z, wv.z, acc[m]);
            acc[m] = fmaf(av.w, wv.w, acc[m]);
        }
    }
    int i8 = col & 7, c8 = col >> 3;
    const float* vbase = &vas[i8][c8 * 8];
    const float* hbase = &hrow[g][c8 * 8];
#pragma unroll
    for (int m = 0; m < 8; ++m) {
        int node = base + g * 8 + m;
        float h = fmaxf(acc[m], 0.f);
        if (node < N) h0[(size_t)node * 64 + col] = h;
        hrow[g][col] = h;            // wave-private LDS, wave-synchronous use
        float r = 0.f;
#pragma unroll
        for (int e = 0; e < 8; ++e)
            r = fmaf(hbase[e], vbase[e], r);
        r += __shfl_xor(r, 8, 64);
        r += __shfl_xor(r, 16, 64);
        r += __shfl_xor(r, 32, 64);
        if (node < N && col < 8) {
            if (col < 4) as_[(size_t)node * 4 + col] = r;
            else         ad_[(size_t)node * 4 + (col - 4)] = r;
        }
    }
}

// ---- h2lin = h1 @ W2: Wt2[64][256], 32 nodes/block, 4 groups x 8, fused att -
__global__ void k_lin2(const float* __restrict__ h1, const float* __restrict__ Wt,
                       const float* __restrict__ att_s, const float* __restrict__ att_d,
                       float* __restrict__ out, float* __restrict__ as_,
                       float* __restrict__ ad_, int N) {
    __shared__ float hs[32][256];
    int base = blockIdx.x * 32;
    int t = threadIdx.x;
    for (int i = 0; i < 8; ++i) {
        int idx4 = t + i * 256;
        int nl = idx4 >> 6, k4 = idx4 & 63;
        int node = base + nl;
        float4 v = make_float4(0.f, 0.f, 0.f, 0.f);
        if (node < N) v = *(const float4*)(h1 + (size_t)node * 256 + k4 * 4);
        *(float4*)&hs[nl][k4 * 4] = v;
    }
    __syncthreads();
    int g = t >> 6, col = t & 63;
    float acc[8] = {};
    const float* wrow = Wt + col * 256;
    for (int k4 = 0; k4 < 64; ++k4) {
        float4 wv = *(const float4*)(wrow + k4 * 4);
#pragma unroll
        for (int m = 0; m < 8; ++m) {
            float4 av = *(const float4*)&hs[g * 8 + m][k4 * 4];
            acc[m] = fmaf(av.x, wv.x, acc[m]);
            acc[m] = fmaf(av.y, wv.y, acc[m]);
            acc[m] = fmaf(av.z, wv.z, acc[m]);
            acc[m] = fmaf(av.w, wv.w, acc[m]);
        }
    }
    float sw = att_s[col], dw = att_d[col];
#pragma unroll
    for (int m = 0; m < 8; ++m) {
        int node = base + g * 8 + m;
        if (node < N) out[(size_t)node * 64 + col] = acc[m];
        float sv = acc[m] * sw, dv = acc[m] * dw;
#pragma unroll
        for (int off = 32; off; off >>= 1) {
            sv += __shfl_xor(sv, off, 64);
            dv += __shfl_xor(dv, off, 64);
        }
        if (col == 0 && node < N) { as_[node] = sv; ad_[node] = dv; }
    }
}

// ------- CSR build over REAL edges only (self-loops handled inline) ----------
__global__ void k_scan_part(const int* __restrict__ deg, int* __restrict__ out,
                            int* __restrict__ partials, int n) {
    __shared__ int wsum[16];
    int b = blockIdx.x, t = threadIdx.x;
    int wv = t >> 6, lane = t & 63;
    int i = b * 1024 + t;
    int v = (i < n) ? deg[i] : 0;
    int s = v;
#pragma unroll
    for (int off = 1; off < 64; off <<= 1) {
        int u = __shfl_up(s, off, 64);
        if (lane >= off) s += u;
    }
    if (lane == 63) wsum[wv] = s;
    __syncthreads();
    if (wv == 0) {
        int ws = (lane < 16) ? wsum[lane] : 0;
#pragma unroll
        for (int off = 1; off < 16; off <<= 1) {
            int u = __shfl_up(ws, off, 64);
            if (lane >= off) ws += u;
        }
        if (lane < 16) wsum[lane] = ws;   // inclusive over waves
    }
    __syncthreads();
    int wbase = (wv == 0) ? 0 : wsum[wv - 1];
    if (i < n) out[i] = wbase + s - v;    // exclusive
    if (t == 1023) partials[b] = wsum[15];
}

__global__ void k_scan_small(int* __restrict__ partials, int nblk) {
    int lane = threadIdx.x & 63;
    int carry = 0;
    for (int base = 0; base < nblk; base += 64) {
        int idx = base + lane;
        int v = (idx < nblk) ? partials[idx] : 0;
        int orig = v;
#pragma unroll
        for (int off = 1; off < 64; off <<= 1) {
            int u = __shfl_up(v, off, 64);
            if (lane >= off) v += u;
        }
        if (idx < nblk) partials[idx] = carry + v - orig; // exclusive
        carry += __shfl(v, 63, 64);
    }
}

__global__ void k_scan_add(int* __restrict__ rowptr, const int* __restrict__ partials,
                           int n, int total) {
    int i = blockIdx.x * 1024 + threadIdx.x;
    if (i < n) rowptr[i] += partials[blockIdx.x];
    if (i == 0) rowptr[n] = total;
}

__global__ void k_scatter(const int* __restrict__ ei, int E,
                          const int* __restrict__ rowptr, int* __restrict__ cursor,
                          int* __restrict__ csrc) {
    for (int i = blockIdx.x * blockDim.x + threadIdx.x; i < E; i += gridDim.x * blockDim.x) {
        int src = ei[i], dst = ei[E + i];
        int pos = rowptr[dst] + atomicAdd(&cursor[dst], 1);
        csrc[pos] = src;
    }
}

// --------- GAT layer 1 fused: inline edge weights + h0 agg + W1 GEMM ---------
// Phase 1: 4 dsts/block, 4 slots x 16 lanes, 2-edge ILP (r17, VALUBusy 82%).
// Phase 2: scalar W1 GLOBAL loads + float4 LDS broadcasts (r10-proven: VGPR 32,
// 78.9us, no spill). r9's spill was float4 GLOBAL weight loads -- keep W1
// scalar. Do not pin unroll 1 (r11) or transpose agg (r13 bank conflicts).
__global__ void k_gat1f(const float* __restrict__ h0, const float* __restrict__ as1,
                        const float* __restrict__ ad1, const int* __restrict__ rowptr,
                        const int* __restrict__ csrc, const float* __restrict__ W1,
                        const float* __restrict__ b1, float* __restrict__ h1out, int N) {
    __shared__ float agg[4][256];
    int t = threadIdx.x, wv = t >> 6, lane = t & 63;
    int slot = lane >> 4, sl = lane & 15;
    int d = blockIdx.x * 4 + wv;
    if (d < N) {
        int s0 = rowptr[d], e0 = rowptr[d + 1];
        float4 ad = *(const float4*)(ad1 + (size_t)d * 4);
        float a00=0,a01=0,a02=0,a03=0;
        float a10=0,a11=0,a12=0,a13=0;
        float a20=0,a21=0,a22=0,a23=0;
        float a30=0,a31=0,a32=0,a33=0;
        float d0=0,d1=0,d2=0,d3=0;
        const float* hb = h0 + sl * 4;
        if (slot == 0) {
            // self-loop
            float4 a = *(const float4*)(as1 + (size_t)d * 4);
            float wx = __expf(lrelu(a.x + ad.x));
            float wy = __expf(lrelu(a.y + ad.y));
            float wz = __expf(lrelu(a.z + ad.z));
            float ww = __expf(lrelu(a.w + ad.w));
            float4 hv = *(const float4*)(hb + (size_t)d * 64);
            a00 = wx*hv.x; a01 = wx*hv.y; a02 = wx*hv.z; a03 = wx*hv.w;
            a10 = wy*hv.x; a11 = wy*hv.y; a12 = wy*hv.z; a13 = wy*hv.w;
            a20 = wz*hv.x; a21 = wz*hv.y; a22 = wz*hv.z; a23 = wz*hv.w;
            a30 = ww*hv.x; a31 = ww*hv.y; a32 = ww*hv.z; a33 = ww*hv.w;
            d0 = wx; d1 = wy; d2 = wz; d3 = ww;
        }
        int j = s0 + slot;
        for (; j + 4 < e0; j += 8) {
            int sA = csrc[j], sB = csrc[j + 4];
            float4 aA = *(const float4*)(as1 + (size_t)sA * 4);
            float4 aB = *(const float4*)(as1 + (size_t)sB * 4);
            float4 hA = *(const float4*)(hb + (size_t)sA * 64);
            float4 hB = *(const float4*)(hb + (size_t)sB * 64);
            float wxA = __expf(lrelu(aA.x + ad.x));
            float wyA = __expf(lrelu(aA.y + ad.y));
            float wzA = __expf(lrelu(aA.z + ad.z));
            float wwA = __expf(lrelu(aA.w + ad.w));
            float wxB = __expf(lrelu(aB.x + ad.x));
            float wyB = __expf(lrelu(aB.y + ad.y));
            float wzB = __expf(lrelu(aB.z + ad.z));
            float wwB = __expf(lrelu(aB.w + ad.w));
            a00 = fmaf(wxA, hA.x, a00); a01 = fmaf(wxA, hA.y, a01);
            a02 = fmaf(wxA, hA.z, a02); a03 = fmaf(wxA, hA.w, a03);
            a10 = fmaf(wyA, hA.x, a10); a11 = fmaf(wyA, hA.y, a11);
            a12 = fmaf(wyA, hA.z, a12); a13 = fmaf(wyA, hA.w, a13);
            a20 = fmaf(wzA, hA.x, a20); a21 = fmaf(wzA, hA.y, a21);
            a22 = fmaf(wzA, hA.z, a22); a23 = fmaf(wzA, hA.w, a23);
            a30 = fmaf(wwA, hA.x, a30); a31 = fmaf(wwA, hA.y, a31);
            a32 = fmaf(wwA, hA.z, a32); a33 = fmaf(wwA, hA.w, a33);
            d0 += wxA; d1 += wyA; d2 += wzA; d3 += wwA;
            a00 = fmaf(wxB, hB.x, a00); a01 = fmaf(wxB, hB.y, a01);
            a02 = fmaf(wxB, hB.z, a02); a03 = fmaf(wxB, hB.w, a03);
            a10 = fmaf(wyB, hB.x, a10); a11 = fmaf(wyB, hB.y, a11);
            a12 = fmaf(wyB, hB.z, a12); a13 = fmaf(wyB, hB.w, a13);
            a20 = fmaf(wzB, hB.x, a20); a21 = fmaf(wzB, hB.y, a21);
            a22 = fmaf(wzB, hB.z, a22); a23 = fmaf(wzB, hB.w, a23);
            a30 = fmaf(wwB, hB.x, a30); a31 = fmaf(wwB, hB.y, a31);
            a32 = fmaf(wwB, hB.z, a32); a33 = fmaf(wwB, hB.w, a33);
            d0 += wxB; d1 += wyB; d2 += wzB; d3 += wwB;
        }
        if (j < e0) {
            int s = csrc[j];
            float4 a = *(const float4*)(as1 + (size_t)s * 4);
            float4 hv = *(const float4*)(hb + (size_t)s * 64);
            float wx = __expf(lrelu(a.x + ad.x));
            float wy = __expf(lrelu(a.y + ad.y));
            float wz = __expf(lrelu(a.z + ad.z));
            float ww = __expf(lrelu(a.w + ad.w));
            a00 = fmaf(wx, hv.x, a00); a01 = fmaf(wx, hv.y, a01);
            a02 = fmaf(wx, hv.z, a02); a03 = fmaf(wx, hv.w, a03);
            a10 = fmaf(wy, hv.x, a10); a11 = fmaf(wy, hv.y, a11);
            a12 = fmaf(wy, hv.z, a12); a13 = fmaf(wy, hv.w, a13);
            a20 = fmaf(wz, hv.x, a20); a21 = fmaf(wz, hv.y, a21);
            a22 = fmaf(wz, hv.z, a22); a23 = fmaf(wz, hv.w, a23);
            a30 = fmaf(ww, hv.x, a30); a31 = fmaf(ww, hv.y, a31);
            a32 = fmaf(ww, hv.z, a32); a33 = fmaf(ww, hv.w, a33);
            d0 += wx; d1 += wy; d2 += wz; d3 += ww;
        }
#pragma unroll
        for (int off = 16; off <= 32; off <<= 1) {
            a00 += __shfl_xor(a00, off, 64); a01 += __shfl_xor(a01, off, 64);
            a02 += __shfl_xor(a02, off, 64); a03 += __shfl_xor(a03, off, 64);
            a10 += __shfl_xor(a10, off, 64); a11 += __shfl_xor(a11, off, 64);
            a12 += __shfl_xor(a12, off, 64); a13 += __shfl_xor(a13, off, 64);
            a20 += __shfl_xor(a20, off, 64); a21 += __shfl_xor(a21, off, 64);
            a22 += __shfl_xor(a22, off, 64); a23 += __shfl_xor(a23, off, 64);
            a30 += __shfl_xor(a30, off, 64); a31 += __shfl_xor(a31, off, 64);
            a32 += __shfl_xor(a32, off, 64); a33 += __shfl_xor(a33, off, 64);
            d0  += __shfl_xor(d0,  off, 64); d1  += __shfl_xor(d1,  off, 64);
            d2  += __shfl_xor(d2,  off, 64); d3  += __shfl_xor(d3,  off, 64);
        }
        if (slot == 0) {
            float i0 = 1.f / d0, i1 = 1.f / d1, i2 = 1.f / d2, i3 = 1.f / d3;
            *(float4*)&agg[wv][  0 + sl * 4] = make_float4(a00*i0, a01*i0, a02*i0, a03*i0);
            *(float4*)&agg[wv][ 64 + sl * 4] = make_float4(a10*i1, a11*i1, a12*i1, a13*i1);
            *(float4*)&agg[wv][128 + sl * 4] = make_float4(a20*i2, a21*i2, a22*i2, a23*i2);
            *(float4*)&agg[wv][192 + sl * 4] = make_float4(a30*i3, a31*i3, a32*i3, a33*i3);
        }
    }
    __syncthreads();
    int h4 = (t >> 6) << 6;  // head base, wave-uniform
    float o0 = 0.f, o1 = 0.f, o2 = 0.f, o3 = 0.f;
    for (int k4 = 0; k4 < 16; ++k4) {
        int k = k4 * 4;
        float w0  = W1[(k + 0) * 256 + t];
        float w1v = W1[(k + 1) * 256 + t];
        float w2v = W1[(k + 2) * 256 + t];
        float w3v = W1[(k + 3) * 256 + t];
        float4 g0 = *(const float4*)&agg[0][h4 + k];
        float4 g1 = *(const float4*)&agg[1][h4 + k];
        float4 g2 = *(const float4*)&agg[2][h4 + k];
        float4 g3 = *(const float4*)&agg[3][h4 + k];
        o0 = fmaf(g0.x, w0, o0); o0 = fmaf(g0.y, w1v, o0);
        o0 = fmaf(g0.z, w2v, o0); o0 = fmaf(g0.w, w3v, o0);
        o1 = fmaf(g1.x, w0, o1); o1 = fmaf(g1.y, w1v, o1);
        o1 = fmaf(g1.z, w2v, o1); o1 = fmaf(g1.w, w3v, o1);
        o2 = fmaf(g2.x, w0, o2); o2 = fmaf(g2.y, w1v, o2);
        o2 = fmaf(g2.z, w2v, o2); o2 = fmaf(g2.w, w3v, o2);
        o3 = fmaf(g3.x, w0, o3); o3 = fmaf(g3.y, w1v, o3);
        o3 = fmaf(g3.z, w2v, o3); o3 = fmaf(g3.w, w3v, o3);
    }
    float bb = b1[t];
    int base = blockIdx.x * 4;
    if (base + 0 < N) h1out[(size_t)(base + 0) * 256 + t] = fmaxf(o0 + bb, 0.f);
    if (base + 1 < N) h1out[(size_t)(base + 1) * 256 + t] = fmaxf(o1 + bb, 0.f);
    if (base + 2 < N) h1out[(size_t)(base + 2) * 256 + t] = fmaxf(o2 + bb, 0.f);
    if (base + 3 < N) h1out[(size_t)(base + 3) * 256 + t] = fmaxf(o3 + bb, 0.f);
}

// --------- GAT layer 2 (1 head): wave per dst, 4-edge ILP, fused classifier --
__global__ void k_gat2(const float* __restrict__ hlin, const float* __restrict__ as2,
                       const float* __restrict__ ad2, const int* __restrict__ rowptr,
                       const int* __restrict__ csrc, const float* __restrict__ bias,
                       const float* __restrict__ clsW, const float* __restrict__ clsB,
                       float* __restrict__ out, int N) {
    int t = threadIdx.x, wv = t >> 6, lane = t & 63;
    int slot = lane >> 4, sl = lane & 15;
    int d = blockIdx.x * 4 + wv;
    if (d >= N) return;
    int s0 = rowptr[d], e0 = rowptr[d + 1];
    float add = ad2[d];
    float ax = 0.f, ay = 0.f, az = 0.f, aw = 0.f, den = 0.f;
    const float* hb = hlin + sl * 4;
    if (slot == 0) {   // self-loop
        float w = __expf(lrelu(as2[d] + add));
        float4 hv = *(const float4*)(hb + (size_t)d * 64);
        ax = w * hv.x; ay = w * hv.y; az = w * hv.z; aw = w * hv.w;
        den = w;
    }
    int j = s0 + slot;
    for (; j + 12 < e0; j += 16) {
        int sA = csrc[j], sB = csrc[j + 4], sC = csrc[j + 8], sD = csrc[j + 12];
        float wA = __expf(lrelu(as2[sA] + add));
        float wB = __expf(lrelu(as2[sB] + add));
        float wC = __expf(lrelu(as2[sC] + add));
        float wD = __expf(lrelu(as2[sD] + add));
        float4 hA = *(const float4*)(hb + (size_t)sA * 64);
        float4 hB = *(const float4*)(hb + (size_t)sB * 64);
        float4 hC = *(const float4*)(hb + (size_t)sC * 64);
        float4 hD = *(const float4*)(hb + (size_t)sD * 64);
        ax = fmaf(wA, hA.x, ax); ay = fmaf(wA, hA.y, ay);
        az = fmaf(wA, hA.z, az); aw = fmaf(wA, hA.w, aw);
        ax = fmaf(wB, hB.x, ax); ay = fmaf(wB, hB.y, ay);
        az = fmaf(wB, hB.z, az); aw = fmaf(wB, hB.w, aw);
        ax = fmaf(wC, hC.x, ax); ay = fmaf(wC, hC.y, ay);
        az = fmaf(wC, hC.z, az); aw = fmaf(wC, hC.w, aw);
        ax = fmaf(wD, hD.x, ax); ay = fmaf(wD, hD.y, ay);
        az = fmaf(wD, hD.z, az); aw = fmaf(wD, hD.w, aw);
        den += wA + wB + wC + wD;
    }
    for (; j < e0; j += 4) {
        int s = csrc[j];
        float w = __expf(lrelu(as2[s] + add));
        float4 hv = *(const float4*)(hb + (size_t)s * 64);
        ax = fmaf(w, hv.x, ax); ay = fmaf(w, hv.y, ay);
        az = fmaf(w, hv.z, az); aw = fmaf(w, hv.w, aw);
        den += w;
    }
#pragma unroll
    for (int off = 16; off <= 32; off <<= 1) {
        ax += __shfl_xor(ax, off, 64); ay += __shfl_xor(ay, off, 64);
        az += __shfl_xor(az, off, 64); aw += __shfl_xor(aw, off, 64);
        den += __shfl_xor(den, off, 64);
    }
    float inv = 1.f / den;
    float4 bb = *(const float4*)(bias + sl * 4);
    float4 cw = *(const float4*)(clsW + sl * 4);
    float p = fmaxf(fmaf(ax, inv, bb.x), 0.f) * cw.x
            + fmaxf(fmaf(ay, inv, bb.y), 0.f) * cw.y
            + fmaxf(fmaf(az, inv, bb.z), 0.f) * cw.z
            + fmaxf(fmaf(aw, inv, bb.w), 0.f) * cw.w;
#pragma unroll
    for (int off = 1; off <= 8; off <<= 1) p += __shfl_xor(p, off, 64);
    if (lane == 0) out[d] = p + clsB[0];
}

extern "C" void kernel_launch(void* const* d_in, const int* in_sizes, int n_in,
                              void* d_out, int out_size, void* d_ws, size_t ws_size,
                              hipStream_t stream) {
    const float* x     = (const float*)d_in[0];
    const int*   ei    = (const int*)d_in[1];
    const float* projW = (const float*)d_in[2];
    const float* projB = (const float*)d_in[3];
    const float* W1    = (const float*)d_in[4];
    const float* as1w  = (const float*)d_in[5];
    const float* ad1w  = (const float*)d_in[6];
    const float* b1    = (const float*)d_in[7];
    const float* W2    = (const float*)d_in[8];
    const float* as2w  = (const float*)d_in[9];
    const float* ad2w  = (const float*)d_in[10];
    const float* b2    = (const float*)d_in[11];
    const float* clsW  = (const float*)d_in[12];
    const float* clsB  = (const float*)d_in[13];
    float* out = (float*)d_out;

    const int N = in_sizes[0] / F_IN;
    const int E = in_sizes[1] / 2;

    char* ws = (char*)d_ws;
    size_t off = 0;
    auto alloc = [&](size_t bytes) -> void* {
        void* p = ws + off;
        off += (bytes + 255) & ~(size_t)255;
        return p;
    };
    float* h0     = (float*)alloc((size_t)N * 64 * 4);   // reused as h2lin
    float* h1     = (float*)alloc((size_t)N * 256 * 4);
    float* as1    = (float*)alloc((size_t)N * 4 * 4);
    float* ad1    = (float*)alloc((size_t)N * 4 * 4);
    float* as2    = (float*)alloc((size_t)N * 4);
    float* ad2    = (float*)alloc((size_t)N * 4);
    int*   dc     = (int*)alloc((size_t)2 * N * 4);      // deg | cursor adjacent
    int*   deg    = dc;
    int*   cursor = dc + N;
    int*   rowptr = (int*)alloc((size_t)(N + 1) * 4);
    int*   parts  = (int*)alloc(1024 * 4);
    int*   csrc   = (int*)alloc((size_t)E * 4);
    float* wt0    = (float*)alloc(64 * KP_PROJ * 4);
    float* wt2    = (float*)alloc(64 * 256 * 4);
    float* va     = (float*)alloc(512 * 4);
    float* h2lin  = h0;

    // zero deg|cursor, then transposes + va + fused degree count (one kernel)
    hipMemsetAsync(dc, 0, (size_t)2 * N * 4, stream);
    const int ntr = 64 * KP_PROJ + 64 * 256 + 512 + E;
    k_trans<<<(ntr + 255) / 256, 256, 0, stream>>>(
        projW, W2, W1, as1w, ad1w, wt0, wt2, va, ei, E, deg);

    // CSR build (real edges only; self-loops inline in aggregation kernels)
    int nblk = (N + 1023) / 1024;
    k_scan_part<<<nblk, 1024, 0, stream>>>(deg, rowptr, parts, N);
    k_scan_small<<<1, 64, 0, stream>>>(parts, nblk);
    k_scan_add<<<nblk, 1024, 0, stream>>>(rowptr, parts, N, E);
    k_scatter<<<1024, 256, 0, stream>>>(ei, E, rowptr, cursor, csrc);

    // MLP in (+ fused as1/ad1 reduction)
    k_proj<<<(N + 31) / 32, 256, 0, stream>>>(x, wt0, projB, va, h0, as1, ad1, N);

    // GAT layer 1 (h0-domain aggregation, edge weights inline, 4 dst/block)
    k_gat1f<<<(N + 3) / 4, 256, 0, stream>>>(h0, as1, ad1, rowptr, csrc, W1, b1, h1, N);

    // GAT layer 2 + classifier (edge weights fused into k_gat2)
    k_lin2<<<(N + 31) / 32, 256, 0, stream>>>(h1, wt2, as2w, ad2w, h2lin, as2, ad2, N);
    k_gat2<<<(N + 3) / 4, 256, 0, stream>>>(h2lin, as2, ad2, rowptr, csrc, b2,
                                            clsW, clsB, out, N);
}

// Round 20
// 303.082 us; speedup vs baseline: 3.6591x; 3.6591x over previous
//
#include <hip/hip_runtime.h>

#define F_IN 165
#define KP_PROJ 168
constexpr float NEG_SLOPE = 0.2f;

// lrelu(z) = max(z, 0.2z) -- 2 VALU inst vs 3 for cmp/cndmask form.
__device__ __forceinline__ float lrelu(float z) { return fmaxf(z, NEG_SLOPE * z); }

// ---- weight transposes + va vectors + workspace zeroing ---------------------
__global__ void k_trans(const float* __restrict__ pw, const float* __restrict__ w2,
                        const float* __restrict__ w1, const float* __restrict__ as1w,
                        const float* __restrict__ ad1w,
                        float* __restrict__ t0, float* __restrict__ t2,
                        float* __restrict__ va, int* __restrict__ dc, int ndc) {
    int i = blockIdx.x * 256 + threadIdx.x;
    const int n0 = 64 * KP_PROJ, n2 = 64 * 256;
    if (i < n0) {
        int c = i / KP_PROJ, r = i - c * KP_PROJ;
        t0[i] = (r < F_IN) ? pw[r * 64 + c] : 0.f;
    } else if (i < n0 + n2) {
        int j = i - n0; int c = j >> 8, r = j & 255;
        t2[j] = w2[r * 64 + c];
    } else if (i < n0 + n2 + 512) {
        int j = i - n0 - n2;          // 0..511
        int i2 = j >> 6;              // 0..7 = plane*4 + h
        int plane = i2 >> 2, h = i2 & 3, k = j & 63;
        const float* att = plane ? ad1w : as1w;
        float acc = 0.f;
        for (int c = 0; c < 64; ++c)
            acc = fmaf(w1[k * 256 + h * 64 + c], att[h * 64 + c], acc);
        va[j] = acc;
    }
    int z = i - (n0 + n2 + 512);
    if (z >= 0 && z < ndc) dc[z] = 0;
}

// ---- h0 = relu(x @ W + b) + fused as1/ad1 via single-wave LDS transpose -----
__global__ void k_proj(const float* __restrict__ x, const float* __restrict__ Wt,
                       const float* __restrict__ b, const float* __restrict__ va,
                       float* __restrict__ h0, float* __restrict__ as_,
                       float* __restrict__ ad_, int N) {
    __shared__ float xs[32][KP_PROJ];
    __shared__ float vas[8][65];
    __shared__ float hrow[4][64];
    int base = blockIdx.x * 32;
    int t = threadIdx.x;
    for (int idx = t; idx < 512; idx += 256)
        vas[idx >> 6][idx & 63] = va[idx];
    for (int idx = t; idx < 32 * KP_PROJ; idx += 256) {
        int nl = idx / KP_PROJ, k = idx - nl * KP_PROJ;
        int node = base + nl;
        xs[nl][k] = (node < N && k < F_IN) ? x[(size_t)node * F_IN + k] : 0.f;
    }
    __syncthreads();
    int g = t >> 6, col = t & 63;
    float acc[8];
    float bb = b[col];
#pragma unroll
    for (int m = 0; m < 8; ++m) acc[m] = bb;
    const float* wrow = Wt + col * KP_PROJ;
    for (int k4 = 0; k4 < KP_PROJ / 4; ++k4) {
        float4 wv = *(const float4*)(wrow + k4 * 4);
#pragma unroll
        for (int m = 0; m < 8; ++m) {
            float4 av = *(const float4*)&xs[g * 8 + m][k4 * 4];
            acc[m] = fmaf(av.x, wv.x, acc[m]);
            acc[m] = fmaf(av.y, wv.y, acc[m]);
            acc[m] = fmaf(av.z, wv.z, acc[m]);
            acc[m] = fmaf(av.w, wv.w, acc[m]);
        }
    }
    int i8 = col & 7, c8 = col >> 3;
    const float* vbase = &vas[i8][c8 * 8];
    const float* hbase = &hrow[g][c8 * 8];
#pragma unroll
    for (int m = 0; m < 8; ++m) {
        int node = base + g * 8 + m;
        float h = fmaxf(acc[m], 0.f);
        if (node < N) h0[(size_t)node * 64 + col] = h;
        hrow[g][col] = h;            // wave-private LDS, wave-synchronous use
        float r = 0.f;
#pragma unroll
        for (int e = 0; e < 8; ++e)
            r = fmaf(hbase[e], vbase[e], r);
        r += __shfl_xor(r, 8, 64);
        r += __shfl_xor(r, 16, 64);
        r += __shfl_xor(r, 32, 64);
        if (node < N && col < 8) {
            if (col < 4) as_[(size_t)node * 4 + col] = r;
            else         ad_[(size_t)node * 4 + (col - 4)] = r;
        }
    }
}

// ---- h2lin = h1 @ W2: Wt2[64][256], 32 nodes/block, 4 groups x 8, fused att -
__global__ void k_lin2(const float* __restrict__ h1, const float* __restrict__ Wt,
                       const float* __restrict__ att_s, const float* __restrict__ att_d,
                       float* __restrict__ out, float* __restrict__ as_,
                       float* __restrict__ ad_, int N) {
    __shared__ float hs[32][256];
    int base = blockIdx.x * 32;
    int t = threadIdx.x;
    for (int i = 0; i < 8; ++i) {
        int idx4 = t + i * 256;
        int nl = idx4 >> 6, k4 = idx4 & 63;
        int node = base + nl;
        float4 v = make_float4(0.f, 0.f, 0.f, 0.f);
        if (node < N) v = *(const float4*)(h1 + (size_t)node * 256 + k4 * 4);
        *(float4*)&hs[nl][k4 * 4] = v;
    }
    __syncthreads();
    int g = t >> 6, col = t & 63;
    float acc[8] = {};
    const float* wrow = Wt + col * 256;
    for (int k4 = 0; k4 < 64; ++k4) {
        float4 wv = *(const float4*)(wrow + k4 * 4);
#pragma unroll
        for (int m = 0; m < 8; ++m) {
            float4 av = *(const float4*)&hs[g * 8 + m][k4 * 4];
            acc[m] = fmaf(av.x, wv.x, acc[m]);
            acc[m] = fmaf(av.y, wv.y, acc[m]);
            acc[m] = fmaf(av.z, wv.z, acc[m]);
            acc[m] = fmaf(av.w, wv.w, acc[m]);
        }
    }
    float sw = att_s[col], dw = att_d[col];
#pragma unroll
    for (int m = 0; m < 8; ++m) {
        int node = base + g * 8 + m;
        if (node < N) out[(size_t)node * 64 + col] = acc[m];
        float sv = acc[m] * sw, dv = acc[m] * dw;
#pragma unroll
        for (int off = 32; off; off >>= 1) {
            sv += __shfl_xor(sv, off, 64);
            dv += __shfl_xor(dv, off, 64);
        }
        if (col == 0 && node < N) { as_[node] = sv; ad_[node] = dv; }
    }
}

// ------- CSR build over REAL edges only (self-loops handled inline) ----------
__global__ void k_deg(const int* __restrict__ ei, int E, int* __restrict__ deg) {
    for (int i = blockIdx.x * blockDim.x + threadIdx.x; i < E; i += gridDim.x * blockDim.x) {
        atomicAdd(&deg[ei[E + i]], 1);
    }
}

__global__ void k_scan_part(const int* __restrict__ deg, int* __restrict__ out,
                            int* __restrict__ partials, int n) {
    __shared__ int tmp[1024];
    int b = blockIdx.x, t = threadIdx.x;
    int i = b * 1024 + t;
    int v = (i < n) ? deg[i] : 0;
    tmp[t] = v;
    __syncthreads();
    for (int off = 1; off < 1024; off <<= 1) {
        int xval = (t >= off) ? tmp[t - off] : 0;
        __syncthreads();
        tmp[t] += xval;
        __syncthreads();
    }
    if (i < n) out[i] = tmp[t] - v; // exclusive
    if (t == 1023) partials[b] = tmp[t];
}

__global__ void k_scan_small(int* __restrict__ partials, int nblk) {
    int lane = threadIdx.x & 63;
    int carry = 0;
    for (int base = 0; base < nblk; base += 64) {
        int idx = base + lane;
        int v = (idx < nblk) ? partials[idx] : 0;
        int orig = v;
#pragma unroll
        for (int off = 1; off < 64; off <<= 1) {
            int u = __shfl_up(v, off, 64);
            if (lane >= off) v += u;
        }
        if (idx < nblk) partials[idx] = carry + v - orig; // exclusive
        carry += __shfl(v, 63, 64);
    }
}

__global__ void k_scan_add(int* __restrict__ rowptr, const int* __restrict__ partials,
                           int n, int total) {
    int i = blockIdx.x * 1024 + threadIdx.x;
    if (i < n) rowptr[i] += partials[blockIdx.x];
    if (i == 0) rowptr[n] = total;
}

__global__ void k_scatter(const int* __restrict__ ei, int E,
                          const int* __restrict__ rowptr, int* __restrict__ cursor,
                          int* __restrict__ csrc) {
    for (int i = blockIdx.x * blockDim.x + threadIdx.x; i < E; i += gridDim.x * blockDim.x) {
        int src = ei[i], dst = ei[E + i];
        int pos = rowptr[dst] + atomicAdd(&cursor[dst], 1);
        csrc[pos] = src;
    }
}

// --------- GAT layer 1 fused: inline edge weights + h0 agg + W1 GEMM ---------
// 4 dsts/block (256 thr). Phase 1: 4 slots x 16 lanes, 2-edge ILP (8 gather
// chains/wave). Phase 2: SCALAR W1 + SCALAR LDS -- the only non-spilling,
// non-slow codegen (r4/5/9/19 spills with float4; r11 unroll-1 slow; r13
// transposed-agg bank conflicts). DO NOT TOUCH PHASE 2.
__global__ void k_gat1f(const float* __restrict__ h0, const float* __restrict__ as1,
                        const float* __restrict__ ad1, const int* __restrict__ rowptr,
                        const int* __restrict__ csrc, const float* __restrict__ W1,
                        const float* __restrict__ b1, float* __restrict__ h1out, int N) {
    __shared__ float agg[4][256];
    int t = threadIdx.x, wv = t >> 6, lane = t & 63;
    int slot = lane >> 4, sl = lane & 15;
    int d = blockIdx.x * 4 + wv;
    if (d < N) {
        int s0 = rowptr[d], e0 = rowptr[d + 1];
        float4 ad = *(const float4*)(ad1 + (size_t)d * 4);
        float a00=0,a01=0,a02=0,a03=0;
        float a10=0,a11=0,a12=0,a13=0;
        float a20=0,a21=0,a22=0,a23=0;
        float a30=0,a31=0,a32=0,a33=0;
        float d0=0,d1=0,d2=0,d3=0;
        const float* hb = h0 + sl * 4;
        if (slot == 0) {
            // self-loop
            float4 a = *(const float4*)(as1 + (size_t)d * 4);
            float wx = __expf(lrelu(a.x + ad.x));
            float wy = __expf(lrelu(a.y + ad.y));
            float wz = __expf(lrelu(a.z + ad.z));
            float ww = __expf(lrelu(a.w + ad.w));
            float4 hv = *(const float4*)(hb + (size_t)d * 64);
            a00 = wx*hv.x; a01 = wx*hv.y; a02 = wx*hv.z; a03 = wx*hv.w;
            a10 = wy*hv.x; a11 = wy*hv.y; a12 = wy*hv.z; a13 = wy*hv.w;
            a20 = wz*hv.x; a21 = wz*hv.y; a22 = wz*hv.z; a23 = wz*hv.w;
            a30 = ww*hv.x; a31 = ww*hv.y; a32 = ww*hv.z; a33 = ww*hv.w;
            d0 = wx; d1 = wy; d2 = wz; d3 = ww;
        }
        int j = s0 + slot;
        for (; j + 4 < e0; j += 8) {
            int sA = csrc[j], sB = csrc[j + 4];
            float4 aA = *(const float4*)(as1 + (size_t)sA * 4);
            float4 aB = *(const float4*)(as1 + (size_t)sB * 4);
            float4 hA = *(const float4*)(hb + (size_t)sA * 64);
            float4 hB = *(const float4*)(hb + (size_t)sB * 64);
            float wxA = __expf(lrelu(aA.x + ad.x));
            float wyA = __expf(lrelu(aA.y + ad.y));
            float wzA = __expf(lrelu(aA.z + ad.z));
            float wwA = __expf(lrelu(aA.w + ad.w));
            float wxB = __expf(lrelu(aB.x + ad.x));
            float wyB = __expf(lrelu(aB.y + ad.y));
            float wzB = __expf(lrelu(aB.z + ad.z));
            float wwB = __expf(lrelu(aB.w + ad.w));
            a00 = fmaf(wxA, hA.x, a00); a01 = fmaf(wxA, hA.y, a01);
            a02 = fmaf(wxA, hA.z, a02); a03 = fmaf(wxA, hA.w, a03);
            a10 = fmaf(wyA, hA.x, a10); a11 = fmaf(wyA, hA.y, a11);
            a12 = fmaf(wyA, hA.z, a12); a13 = fmaf(wyA, hA.w, a13);
            a20 = fmaf(wzA, hA.x, a20); a21 = fmaf(wzA, hA.y, a21);
            a22 = fmaf(wzA, hA.z, a22); a23 = fmaf(wzA, hA.w, a23);
            a30 = fmaf(wwA, hA.x, a30); a31 = fmaf(wwA, hA.y, a31);
            a32 = fmaf(wwA, hA.z, a32); a33 = fmaf(wwA, hA.w, a33);
            d0 += wxA; d1 += wyA; d2 += wzA; d3 += wwA;
            a00 = fmaf(wxB, hB.x, a00); a01 = fmaf(wxB, hB.y, a01);
            a02 = fmaf(wxB, hB.z, a02); a03 = fmaf(wxB, hB.w, a03);
            a10 = fmaf(wyB, hB.x, a10); a11 = fmaf(wyB, hB.y, a11);
            a12 = fmaf(wyB, hB.z, a12); a13 = fmaf(wyB, hB.w, a13);
            a20 = fmaf(wzB, hB.x, a20); a21 = fmaf(wzB, hB.y, a21);
            a22 = fmaf(wzB, hB.z, a22); a23 = fmaf(wzB, hB.w, a23);
            a30 = fmaf(wwB, hB.x, a30); a31 = fmaf(wwB, hB.y, a31);
            a32 = fmaf(wwB, hB.z, a32); a33 = fmaf(wwB, hB.w, a33);
            d0 += wxB; d1 += wyB; d2 += wzB; d3 += wwB;
        }
        if (j < e0) {
            int s = csrc[j];
            float4 a = *(const float4*)(as1 + (size_t)s * 4);
            float4 hv = *(const float4*)(hb + (size_t)s * 64);
            float wx = __expf(lrelu(a.x + ad.x));
            float wy = __expf(lrelu(a.y + ad.y));
            float wz = __expf(lrelu(a.z + ad.z));
            float ww = __expf(lrelu(a.w + ad.w));
            a00 = fmaf(wx, hv.x, a00); a01 = fmaf(wx, hv.y, a01);
            a02 = fmaf(wx, hv.z, a02); a03 = fmaf(wx, hv.w, a03);
            a10 = fmaf(wy, hv.x, a10); a11 = fmaf(wy, hv.y, a11);
            a12 = fmaf(wy, hv.z, a12); a13 = fmaf(wy, hv.w, a13);
            a20 = fmaf(wz, hv.x, a20); a21 = fmaf(wz, hv.y, a21);
            a22 = fmaf(wz, hv.z, a22); a23 = fmaf(wz, hv.w, a23);
            a30 = fmaf(ww, hv.x, a30); a31 = fmaf(ww, hv.y, a31);
            a32 = fmaf(ww, hv.z, a32); a33 = fmaf(ww, hv.w, a33);
            d0 += wx; d1 += wy; d2 += wz; d3 += ww;
        }
#pragma unroll
        for (int off = 16; off <= 32; off <<= 1) {
            a00 += __shfl_xor(a00, off, 64); a01 += __shfl_xor(a01, off, 64);
            a02 += __shfl_xor(a02, off, 64); a03 += __shfl_xor(a03, off, 64);
            a10 += __shfl_xor(a10, off, 64); a11 += __shfl_xor(a11, off, 64);
            a12 += __shfl_xor(a12, off, 64); a13 += __shfl_xor(a13, off, 64);
            a20 += __shfl_xor(a20, off, 64); a21 += __shfl_xor(a21, off, 64);
            a22 += __shfl_xor(a22, off, 64); a23 += __shfl_xor(a23, off, 64);
            a30 += __shfl_xor(a30, off, 64); a31 += __shfl_xor(a31, off, 64);
            a32 += __shfl_xor(a32, off, 64); a33 += __shfl_xor(a33, off, 64);
            d0  += __shfl_xor(d0,  off, 64); d1  += __shfl_xor(d1,  off, 64);
            d2  += __shfl_xor(d2,  off, 64); d3  += __shfl_xor(d3,  off, 64);
        }
        if (slot == 0) {
            float i0 = 1.f / d0, i1 = 1.f / d1, i2 = 1.f / d2, i3 = 1.f / d3;
            *(float4*)&agg[wv][  0 + sl * 4] = make_float4(a00*i0, a01*i0, a02*i0, a03*i0);
            *(float4*)&agg[wv][ 64 + sl * 4] = make_float4(a10*i1, a11*i1, a12*i1, a13*i1);
            *(float4*)&agg[wv][128 + sl * 4] = make_float4(a20*i2, a21*i2, a22*i2, a23*i2);
            *(float4*)&agg[wv][192 + sl * 4] = make_float4(a30*i3, a31*i3, a32*i3, a33*i3);
        }
    }
    __syncthreads();
    int h = t >> 6;
    float o0 = 0.f, o1 = 0.f, o2 = 0.f, o3 = 0.f;
    for (int k = 0; k < 64; ++k) {
        float wv1 = W1[k * 256 + t];
        o0 = fmaf(agg[0][h * 64 + k], wv1, o0);
        o1 = fmaf(agg[1][h * 64 + k], wv1, o1);
        o2 = fmaf(agg[2][h * 64 + k], wv1, o2);
        o3 = fmaf(agg[3][h * 64 + k], wv1, o3);
    }
    float bb = b1[t];
    int base = blockIdx.x * 4;
    if (base + 0 < N) h1out[(size_t)(base + 0) * 256 + t] = fmaxf(o0 + bb, 0.f);
    if (base + 1 < N) h1out[(size_t)(base + 1) * 256 + t] = fmaxf(o1 + bb, 0.f);
    if (base + 2 < N) h1out[(size_t)(base + 2) * 256 + t] = fmaxf(o2 + bb, 0.f);
    if (base + 3 < N) h1out[(size_t)(base + 3) * 256 + t] = fmaxf(o3 + bb, 0.f);
}

// --------- GAT layer 2 (1 head): wave per dst, 2-edge ILP, fused classifier --
__global__ void k_gat2(const float* __restrict__ hlin, const float* __restrict__ as2,
                       const float* __restrict__ ad2, const int* __restrict__ rowptr,
                       const int* __restrict__ csrc, const float* __restrict__ bias,
                       const float* __restrict__ clsW, const float* __restrict__ clsB,
                       float* __restrict__ out, int N) {
    int t = threadIdx.x, wv = t >> 6, lane = t & 63;
    int slot = lane >> 4, sl = lane & 15;
    int d = blockIdx.x * 4 + wv;
    if (d >= N) return;
    int s0 = rowptr[d], e0 = rowptr[d + 1];
    float add = ad2[d];
    float ax = 0.f, ay = 0.f, az = 0.f, aw = 0.f, den = 0.f;
    const float* hb = hlin + sl * 4;
    if (slot == 0) {   // self-loop
        float w = __expf(lrelu(as2[d] + add));
        float4 hv = *(const float4*)(hb + (size_t)d * 64);
        ax = w * hv.x; ay = w * hv.y; az = w * hv.z; aw = w * hv.w;
        den = w;
    }
    int j = s0 + slot;
    for (; j + 4 < e0; j += 8) {
        int sA = csrc[j], sB = csrc[j + 4];
        float wA = __expf(lrelu(as2[sA] + add));
        float wB = __expf(lrelu(as2[sB] + add));
        float4 hA = *(const float4*)(hb + (size_t)sA * 64);
        float4 hB = *(const float4*)(hb + (size_t)sB * 64);
        ax = fmaf(wA, hA.x, ax); ay = fmaf(wA, hA.y, ay);
        az = fmaf(wA, hA.z, az); aw = fmaf(wA, hA.w, aw);
        den += wA;
        ax = fmaf(wB, hB.x, ax); ay = fmaf(wB, hB.y, ay);
        az = fmaf(wB, hB.z, az); aw = fmaf(wB, hB.w, aw);
        den += wB;
    }
    if (j < e0) {
        int s = csrc[j];
        float w = __expf(lrelu(as2[s] + add));
        float4 hv = *(const float4*)(hb + (size_t)s * 64);
        ax = fmaf(w, hv.x, ax); ay = fmaf(w, hv.y, ay);
        az = fmaf(w, hv.z, az); aw = fmaf(w, hv.w, aw);
        den += w;
    }
#pragma unroll
    for (int off = 16; off <= 32; off <<= 1) {
        ax += __shfl_xor(ax, off, 64); ay += __shfl_xor(ay, off, 64);
        az += __shfl_xor(az, off, 64); aw += __shfl_xor(aw, off, 64);
        den += __shfl_xor(den, off, 64);
    }
    float inv = 1.f / den;
    float4 bb = *(const float4*)(bias + sl * 4);
    float4 cw = *(const float4*)(clsW + sl * 4);
    float p = fmaxf(fmaf(ax, inv, bb.x), 0.f) * cw.x
            + fmaxf(fmaf(ay, inv, bb.y), 0.f) * cw.y
            + fmaxf(fmaf(az, inv, bb.z), 0.f) * cw.z
            + fmaxf(fmaf(aw, inv, bb.w), 0.f) * cw.w;
#pragma unroll
    for (int off = 1; off <= 8; off <<= 1) p += __shfl_xor(p, off, 64);
    if (lane == 0) out[d] = p + clsB[0];
}

extern "C" void kernel_launch(void* const* d_in, const int* in_sizes, int n_in,
                              void* d_out, int out_size, void* d_ws, size_t ws_size,
                              hipStream_t stream) {
    const float* x     = (const float*)d_in[0];
    const int*   ei    = (const int*)d_in[1];
    const float* projW = (const float*)d_in[2];
    const float* projB = (const float*)d_in[3];
    const float* W1    = (const float*)d_in[4];
    const float* as1w  = (const float*)d_in[5];
    const float* ad1w  = (const float*)d_in[6];
    const float* b1    = (const float*)d_in[7];
    const float* W2    = (const float*)d_in[8];
    const float* as2w  = (const float*)d_in[9];
    const float* ad2w  = (const float*)d_in[10];
    const float* b2    = (const float*)d_in[11];
    const float* clsW  = (const float*)d_in[12];
    const float* clsB  = (const float*)d_in[13];
    float* out = (float*)d_out;

    const int N = in_sizes[0] / F_IN;
    const int E = in_sizes[1] / 2;

    char* ws = (char*)d_ws;
    size_t off = 0;
    auto alloc = [&](size_t bytes) -> void* {
        void* p = ws + off;
        off += (bytes + 255) & ~(size_t)255;
        return p;
    };
    float* h0     = (float*)alloc((size_t)N * 64 * 4);   // reused as h2lin
    float* h1     = (float*)alloc((size_t)N * 256 * 4);
    float* as1    = (float*)alloc((size_t)N * 4 * 4);
    float* ad1    = (float*)alloc((size_t)N * 4 * 4);
    float* as2    = (float*)alloc((size_t)N * 4);
    float* ad2    = (float*)alloc((size_t)N * 4);
    int*   dc     = (int*)alloc((size_t)2 * N * 4);      // deg | cursor adjacent
    int*   deg    = dc;
    int*   cursor = dc + N;
    int*   rowptr = (int*)alloc((size_t)(N + 1) * 4);
    int*   parts  = (int*)alloc(1024 * 4);
    int*   csrc   = (int*)alloc((size_t)E * 4);
    float* wt0    = (float*)alloc(64 * KP_PROJ * 4);
    float* wt2    = (float*)alloc(64 * 256 * 4);
    float* va     = (float*)alloc(512 * 4);
    float* h2lin  = h0;

    // weight transposes + va vectors + deg/cursor zeroing (one dispatch)
    const int ntr = 64 * KP_PROJ + 64 * 256 + 512 + 2 * N;
    k_trans<<<(ntr + 255) / 256, 256, 0, stream>>>(
        projW, W2, W1, as1w, ad1w, wt0, wt2, va, dc, 2 * N);

    // CSR build (real edges only; self-loops inline in aggregation kernels)
    k_deg<<<1024, 256, 0, stream>>>(ei, E, deg);
    int nblk = (N + 1023) / 1024;
    k_scan_part<<<nblk, 1024, 0, stream>>>(deg, rowptr, parts, N);
    k_scan_small<<<1, 64, 0, stream>>>(parts, nblk);
    k_scan_add<<<nblk, 1024, 0, stream>>>(rowptr, parts, N, E);
    k_scatter<<<1024, 256, 0, stream>>>(ei, E, rowptr, cursor, csrc);

    // MLP in (+ fused as1/ad1 reduction)
    k_proj<<<(N + 31) / 32, 256, 0, stream>>>(x, wt0, projB, va, h0, as1, ad1, N);

    // GAT layer 1 (h0-domain aggregation, edge weights inline, 4 dst/block)
    k_gat1f<<<(N + 3) / 4, 256, 0, stream>>>(h0, as1, ad1, rowptr, csrc, W1, b1, h1, N);

    // GAT layer 2 + classifier (edge weights fused into k_gat2)
    k_lin2<<<(N + 31) / 32, 256, 0, stream>>>(h1, wt2, as2w, ad2w, h2lin, as2, ad2, N);
    k_gat2<<<(N + 3) / 4, 256, 0, stream>>>(h2lin, as2, ad2, rowptr, csrc, b2,
                                            clsW, clsB, out, N);
}

// Round 21
// 301.841 us; speedup vs baseline: 3.6741x; 1.0041x over previous
//
#include <hip/hip_runtime.h>

#define F_IN 165
#define KP_PROJ 168
constexpr float NEG_SLOPE = 0.2f;

// lrelu(z) = max(z, 0.2z) -- 2 VALU inst vs 3 for cmp/cndmask form.
__device__ __forceinline__ float lrelu(float z) { return fmaxf(z, NEG_SLOPE * z); }

// ---- weight transposes + va vectors + workspace zeroing ---------------------
__global__ void k_trans(const float* __restrict__ pw, const float* __restrict__ w2,
                        const float* __restrict__ w1, const float* __restrict__ as1w,
                        const float* __restrict__ ad1w,
                        float* __restrict__ t0, float* __restrict__ t2,
                        float* __restrict__ va, int* __restrict__ dc, int ndc) {
    int i = blockIdx.x * 256 + threadIdx.x;
    const int n0 = 64 * KP_PROJ, n2 = 64 * 256;
    if (i < n0) {
        int c = i / KP_PROJ, r = i - c * KP_PROJ;
        t0[i] = (r < F_IN) ? pw[r * 64 + c] : 0.f;
    } else if (i < n0 + n2) {
        int j = i - n0; int c = j >> 8, r = j & 255;
        t2[j] = w2[r * 64 + c];
    } else if (i < n0 + n2 + 512) {
        int j = i - n0 - n2;          // 0..511
        int i2 = j >> 6;              // 0..7 = plane*4 + h
        int plane = i2 >> 2, h = i2 & 3, k = j & 63;
        const float* att = plane ? ad1w : as1w;
        float acc = 0.f;
        for (int c = 0; c < 64; ++c)
            acc = fmaf(w1[k * 256 + h * 64 + c], att[h * 64 + c], acc);
        va[j] = acc;
    }
    int z = i - (n0 + n2 + 512);
    if (z >= 0 && z < ndc) dc[z] = 0;
}

// ---- h0 = relu(x @ W + b) + fused as1/ad1 via single-wave LDS transpose -----
__global__ void k_proj(const float* __restrict__ x, const float* __restrict__ Wt,
                       const float* __restrict__ b, const float* __restrict__ va,
                       float* __restrict__ h0, float* __restrict__ as_,
                       float* __restrict__ ad_, int N) {
    __shared__ float xs[32][KP_PROJ];
    __shared__ float vas[8][65];
    __shared__ float hrow[4][64];
    int base = blockIdx.x * 32;
    int t = threadIdx.x;
    for (int idx = t; idx < 512; idx += 256)
        vas[idx >> 6][idx & 63] = va[idx];
    for (int idx = t; idx < 32 * KP_PROJ; idx += 256) {
        int nl = idx / KP_PROJ, k = idx - nl * KP_PROJ;
        int node = base + nl;
        xs[nl][k] = (node < N && k < F_IN) ? x[(size_t)node * F_IN + k] : 0.f;
    }
    __syncthreads();
    int g = t >> 6, col = t & 63;
    float acc[8];
    float bb = b[col];
#pragma unroll
    for (int m = 0; m < 8; ++m) acc[m] = bb;
    const float* wrow = Wt + col * KP_PROJ;
    for (int k4 = 0; k4 < KP_PROJ / 4; ++k4) {
        float4 wv = *(const float4*)(wrow + k4 * 4);
#pragma unroll
        for (int m = 0; m < 8; ++m) {
            float4 av = *(const float4*)&xs[g * 8 + m][k4 * 4];
            acc[m] = fmaf(av.x, wv.x, acc[m]);
            acc[m] = fmaf(av.y, wv.y, acc[m]);
            acc[m] = fmaf(av.z, wv.z, acc[m]);
            acc[m] = fmaf(av.w, wv.w, acc[m]);
        }
    }
    int i8 = col & 7, c8 = col >> 3;
    const float* vbase = &vas[i8][c8 * 8];
    const float* hbase = &hrow[g][c8 * 8];
#pragma unroll
    for (int m = 0; m < 8; ++m) {
        int node = base + g * 8 + m;
        float h = fmaxf(acc[m], 0.f);
        if (node < N) h0[(size_t)node * 64 + col] = h;
        hrow[g][col] = h;            // wave-private LDS, wave-synchronous use
        float r = 0.f;
#pragma unroll
        for (int e = 0; e < 8; ++e)
            r = fmaf(hbase[e], vbase[e], r);
        r += __shfl_xor(r, 8, 64);
        r += __shfl_xor(r, 16, 64);
        r += __shfl_xor(r, 32, 64);
        if (node < N && col < 8) {
            if (col < 4) as_[(size_t)node * 4 + col] = r;
            else         ad_[(size_t)node * 4 + (col - 4)] = r;
        }
    }
}

// ---- h2lin = h1 @ W2: Wt2[64][256], 32 nodes/block, 4 groups x 8, fused att -
__global__ void k_lin2(const float* __restrict__ h1, const float* __restrict__ Wt,
                       const float* __restrict__ att_s, const float* __restrict__ att_d,
                       float* __restrict__ out, float* __restrict__ as_,
                       float* __restrict__ ad_, int N) {
    __shared__ float hs[32][256];
    int base = blockIdx.x * 32;
    int t = threadIdx.x;
    for (int i = 0; i < 8; ++i) {
        int idx4 = t + i * 256;
        int nl = idx4 >> 6, k4 = idx4 & 63;
        int node = base + nl;
        float4 v = make_float4(0.f, 0.f, 0.f, 0.f);
        if (node < N) v = *(const float4*)(h1 + (size_t)node * 256 + k4 * 4);
        *(float4*)&hs[nl][k4 * 4] = v;
    }
    __syncthreads();
    int g = t >> 6, col = t & 63;
    float acc[8] = {};
    const float* wrow = Wt + col * 256;
    for (int k4 = 0; k4 < 64; ++k4) {
        float4 wv = *(const float4*)(wrow + k4 * 4);
#pragma unroll
        for (int m = 0; m < 8; ++m) {
            float4 av = *(const float4*)&hs[g * 8 + m][k4 * 4];
            acc[m] = fmaf(av.x, wv.x, acc[m]);
            acc[m] = fmaf(av.y, wv.y, acc[m]);
            acc[m] = fmaf(av.z, wv.z, acc[m]);
            acc[m] = fmaf(av.w, wv.w, acc[m]);
        }
    }
    float sw = att_s[col], dw = att_d[col];
#pragma unroll
    for (int m = 0; m < 8; ++m) {
        int node = base + g * 8 + m;
        if (node < N) out[(size_t)node * 64 + col] = acc[m];
        float sv = acc[m] * sw, dv = acc[m] * dw;
#pragma unroll
        for (int off = 32; off; off >>= 1) {
            sv += __shfl_xor(sv, off, 64);
            dv += __shfl_xor(dv, off, 64);
        }
        if (col == 0 && node < N) { as_[node] = sv; ad_[node] = dv; }
    }
}

// ------- CSR build over REAL edges only (self-loops handled inline) ----------
__global__ void k_deg(const int* __restrict__ ei, int E, int* __restrict__ deg) {
    for (int i = blockIdx.x * blockDim.x + threadIdx.x; i < E; i += gridDim.x * blockDim.x) {
        atomicAdd(&deg[ei[E + i]], 1);
    }
}

__global__ void k_scan_part(const int* __restrict__ deg, int* __restrict__ out,
                            int* __restrict__ partials, int n) {
    __shared__ int tmp[1024];
    int b = blockIdx.x, t = threadIdx.x;
    int i = b * 1024 + t;
    int v = (i < n) ? deg[i] : 0;
    tmp[t] = v;
    __syncthreads();
    for (int off = 1; off < 1024; off <<= 1) {
        int xval = (t >= off) ? tmp[t - off] : 0;
        __syncthreads();
        tmp[t] += xval;
        __syncthreads();
    }
    if (i < n) out[i] = tmp[t] - v; // exclusive
    if (t == 1023) partials[b] = tmp[t];
}

__global__ void k_scan_small(int* __restrict__ partials, int nblk) {
    int lane = threadIdx.x & 63;
    int carry = 0;
    for (int base = 0; base < nblk; base += 64) {
        int idx = base + lane;
        int v = (idx < nblk) ? partials[idx] : 0;
        int orig = v;
#pragma unroll
        for (int off = 1; off < 64; off <<= 1) {
            int u = __shfl_up(v, off, 64);
            if (lane >= off) v += u;
        }
        if (idx < nblk) partials[idx] = carry + v - orig; // exclusive
        carry += __shfl(v, 63, 64);
    }
}

__global__ void k_scan_add(int* __restrict__ rowptr, const int* __restrict__ partials,
                           int n, int total) {
    int i = blockIdx.x * 1024 + threadIdx.x;
    if (i < n) rowptr[i] += partials[blockIdx.x];
    if (i == 0) rowptr[n] = total;
}

// ---- scatter + fused layer-1 edge weights (full lane-efficiency exp) --------
// Computes wexp4[pos] = exp(lrelu(as1[src] + ad1[dst])) while scattering.
// as1/ad1 are L2-resident (800 KB each); removes the 16x-redundant per-lane
// exp from k_gat1f's phase-1 inner loop.
__global__ void k_scatter(const int* __restrict__ ei, int E,
                          const int* __restrict__ rowptr, int* __restrict__ cursor,
                          const float* __restrict__ as1, const float* __restrict__ ad1,
                          int* __restrict__ csrc, float* __restrict__ wexp) {
    for (int i = blockIdx.x * blockDim.x + threadIdx.x; i < E; i += gridDim.x * blockDim.x) {
        int src = ei[i], dst = ei[E + i];
        int pos = rowptr[dst] + atomicAdd(&cursor[dst], 1);
        csrc[pos] = src;
        float4 a = *(const float4*)(as1 + (size_t)src * 4);
        float4 b = *(const float4*)(ad1 + (size_t)dst * 4);
        float4 w;
        w.x = __expf(lrelu(a.x + b.x));
        w.y = __expf(lrelu(a.y + b.y));
        w.z = __expf(lrelu(a.z + b.z));
        w.w = __expf(lrelu(a.w + b.w));
        *(float4*)(wexp + (size_t)pos * 4) = w;
    }
}

// --------- GAT layer 1 fused: precomputed wexp4 + h0 agg + W1 GEMM -----------
// Phase 1: 4 dsts/block, 4 slots x 16 lanes, 2-edge ILP; weights come from
// wexp4[j] (slot-uniform 16B broadcast) -- no redundant exp (r10+r17 combo).
// Phase 2: SCALAR W1 + SCALAR LDS -- the only non-spilling, non-slow codegen
// (r4/5/9/19 spills with float4; r11 unroll-1 slow; r13 transposed-agg bank
// conflicts). DO NOT TOUCH PHASE 2.
__global__ void k_gat1f(const float* __restrict__ h0, const float* __restrict__ wexp4,
                        const float* __restrict__ as1, const float* __restrict__ ad1,
                        const int* __restrict__ rowptr, const int* __restrict__ csrc,
                        const float* __restrict__ W1, const float* __restrict__ b1,
                        float* __restrict__ h1out, int N) {
    __shared__ float agg[4][256];
    int t = threadIdx.x, wv = t >> 6, lane = t & 63;
    int slot = lane >> 4, sl = lane & 15;
    int d = blockIdx.x * 4 + wv;
    if (d < N) {
        int s0 = rowptr[d], e0 = rowptr[d + 1];
        float a00=0,a01=0,a02=0,a03=0;
        float a10=0,a11=0,a12=0,a13=0;
        float a20=0,a21=0,a22=0,a23=0;
        float a30=0,a31=0,a32=0,a33=0;
        float d0=0,d1=0,d2=0,d3=0;
        const float* hb = h0 + sl * 4;
        if (slot == 0) {
            // self-loop (weights computed inline, slot 0 only)
            float4 a = *(const float4*)(as1 + (size_t)d * 4);
            float4 b = *(const float4*)(ad1 + (size_t)d * 4);
            float wx = __expf(lrelu(a.x + b.x));
            float wy = __expf(lrelu(a.y + b.y));
            float wz = __expf(lrelu(a.z + b.z));
            float ww = __expf(lrelu(a.w + b.w));
            float4 hv = *(const float4*)(hb + (size_t)d * 64);
            a00 = wx*hv.x; a01 = wx*hv.y; a02 = wx*hv.z; a03 = wx*hv.w;
            a10 = wy*hv.x; a11 = wy*hv.y; a12 = wy*hv.z; a13 = wy*hv.w;
            a20 = wz*hv.x; a21 = wz*hv.y; a22 = wz*hv.z; a23 = wz*hv.w;
            a30 = ww*hv.x; a31 = ww*hv.y; a32 = ww*hv.z; a33 = ww*hv.w;
            d0 = wx; d1 = wy; d2 = wz; d3 = ww;
        }
        int j = s0 + slot;
        for (; j + 4 < e0; j += 8) {
            int sA = csrc[j], sB = csrc[j + 4];
            float4 wA = *(const float4*)(wexp4 + (size_t)j * 4);
            float4 wB = *(const float4*)(wexp4 + (size_t)(j + 4) * 4);
            float4 hA = *(const float4*)(hb + (size_t)sA * 64);
            float4 hB = *(const float4*)(hb + (size_t)sB * 64);
            a00 = fmaf(wA.x, hA.x, a00); a01 = fmaf(wA.x, hA.y, a01);
            a02 = fmaf(wA.x, hA.z, a02); a03 = fmaf(wA.x, hA.w, a03);
            a10 = fmaf(wA.y, hA.x, a10); a11 = fmaf(wA.y, hA.y, a11);
            a12 = fmaf(wA.y, hA.z, a12); a13 = fmaf(wA.y, hA.w, a13);
            a20 = fmaf(wA.z, hA.x, a20); a21 = fmaf(wA.z, hA.y, a21);
            a22 = fmaf(wA.z, hA.z, a22); a23 = fmaf(wA.z, hA.w, a23);
            a30 = fmaf(wA.w, hA.x, a30); a31 = fmaf(wA.w, hA.y, a31);
            a32 = fmaf(wA.w, hA.z, a32); a33 = fmaf(wA.w, hA.w, a33);
            d0 += wA.x; d1 += wA.y; d2 += wA.z; d3 += wA.w;
            a00 = fmaf(wB.x, hB.x, a00); a01 = fmaf(wB.x, hB.y, a01);
            a02 = fmaf(wB.x, hB.z, a02); a03 = fmaf(wB.x, hB.w, a03);
            a10 = fmaf(wB.y, hB.x, a10); a11 = fmaf(wB.y, hB.y, a11);
            a12 = fmaf(wB.y, hB.z, a12); a13 = fmaf(wB.y, hB.w, a13);
            a20 = fmaf(wB.z, hB.x, a20); a21 = fmaf(wB.z, hB.y, a21);
            a22 = fmaf(wB.z, hB.z, a22); a23 = fmaf(wB.z, hB.w, a23);
            a30 = fmaf(wB.w, hB.x, a30); a31 = fmaf(wB.w, hB.y, a31);
            a32 = fmaf(wB.w, hB.z, a32); a33 = fmaf(wB.w, hB.w, a33);
            d0 += wB.x; d1 += wB.y; d2 += wB.z; d3 += wB.w;
        }
        if (j < e0) {
            int s = csrc[j];
            float4 w = *(const float4*)(wexp4 + (size_t)j * 4);
            float4 hv = *(const float4*)(hb + (size_t)s * 64);
            a00 = fmaf(w.x, hv.x, a00); a01 = fmaf(w.x, hv.y, a01);
            a02 = fmaf(w.x, hv.z, a02); a03 = fmaf(w.x, hv.w, a03);
            a10 = fmaf(w.y, hv.x, a10); a11 = fmaf(w.y, hv.y, a11);
            a12 = fmaf(w.y, hv.z, a12); a13 = fmaf(w.y, hv.w, a13);
            a20 = fmaf(w.z, hv.x, a20); a21 = fmaf(w.z, hv.y, a21);
            a22 = fmaf(w.z, hv.z, a22); a23 = fmaf(w.z, hv.w, a23);
            a30 = fmaf(w.w, hv.x, a30); a31 = fmaf(w.w, hv.y, a31);
            a32 = fmaf(w.w, hv.z, a32); a33 = fmaf(w.w, hv.w, a33);
            d0 += w.x; d1 += w.y; d2 += w.z; d3 += w.w;
        }
#pragma unroll
        for (int off = 16; off <= 32; off <<= 1) {
            a00 += __shfl_xor(a00, off, 64); a01 += __shfl_xor(a01, off, 64);
            a02 += __shfl_xor(a02, off, 64); a03 += __shfl_xor(a03, off, 64);
            a10 += __shfl_xor(a10, off, 64); a11 += __shfl_xor(a11, off, 64);
            a12 += __shfl_xor(a12, off, 64); a13 += __shfl_xor(a13, off, 64);
            a20 += __shfl_xor(a20, off, 64); a21 += __shfl_xor(a21, off, 64);
            a22 += __shfl_xor(a22, off, 64); a23 += __shfl_xor(a23, off, 64);
            a30 += __shfl_xor(a30, off, 64); a31 += __shfl_xor(a31, off, 64);
            a32 += __shfl_xor(a32, off, 64); a33 += __shfl_xor(a33, off, 64);
            d0  += __shfl_xor(d0,  off, 64); d1  += __shfl_xor(d1,  off, 64);
            d2  += __shfl_xor(d2,  off, 64); d3  += __shfl_xor(d3,  off, 64);
        }
        if (slot == 0) {
            float i0 = 1.f / d0, i1 = 1.f / d1, i2 = 1.f / d2, i3 = 1.f / d3;
            *(float4*)&agg[wv][  0 + sl * 4] = make_float4(a00*i0, a01*i0, a02*i0, a03*i0);
            *(float4*)&agg[wv][ 64 + sl * 4] = make_float4(a10*i1, a11*i1, a12*i1, a13*i1);
            *(float4*)&agg[wv][128 + sl * 4] = make_float4(a20*i2, a21*i2, a22*i2, a23*i2);
            *(float4*)&agg[wv][192 + sl * 4] = make_float4(a30*i3, a31*i3, a32*i3, a33*i3);
        }
    }
    __syncthreads();
    int h = t >> 6;
    float o0 = 0.f, o1 = 0.f, o2 = 0.f, o3 = 0.f;
    for (int k = 0; k < 64; ++k) {
        float wv1 = W1[k * 256 + t];
        o0 = fmaf(agg[0][h * 64 + k], wv1, o0);
        o1 = fmaf(agg[1][h * 64 + k], wv1, o1);
        o2 = fmaf(agg[2][h * 64 + k], wv1, o2);
        o3 = fmaf(agg[3][h * 64 + k], wv1, o3);
    }
    float bb = b1[t];
    int base = blockIdx.x * 4;
    if (base + 0 < N) h1out[(size_t)(base + 0) * 256 + t] = fmaxf(o0 + bb, 0.f);
    if (base + 1 < N) h1out[(size_t)(base + 1) * 256 + t] = fmaxf(o1 + bb, 0.f);
    if (base + 2 < N) h1out[(size_t)(base + 2) * 256 + t] = fmaxf(o2 + bb, 0.f);
    if (base + 3 < N) h1out[(size_t)(base + 3) * 256 + t] = fmaxf(o3 + bb, 0.f);
}

// --------- GAT layer 2 (1 head): wave per dst, 2-edge ILP, fused classifier --
__global__ void k_gat2(const float* __restrict__ hlin, const float* __restrict__ as2,
                       const float* __restrict__ ad2, const int* __restrict__ rowptr,
                       const int* __restrict__ csrc, const float* __restrict__ bias,
                       const float* __restrict__ clsW, const float* __restrict__ clsB,
                       float* __restrict__ out, int N) {
    int t = threadIdx.x, wv = t >> 6, lane = t & 63;
    int slot = lane >> 4, sl = lane & 15;
    int d = blockIdx.x * 4 + wv;
    if (d >= N) return;
    int s0 = rowptr[d], e0 = rowptr[d + 1];
    float add = ad2[d];
    float ax = 0.f, ay = 0.f, az = 0.f, aw = 0.f, den = 0.f;
    const float* hb = hlin + sl * 4;
    if (slot == 0) {   // self-loop
        float w = __expf(lrelu(as2[d] + add));
        float4 hv = *(const float4*)(hb + (size_t)d * 64);
        ax = w * hv.x; ay = w * hv.y; az = w * hv.z; aw = w * hv.w;
        den = w;
    }
    int j = s0 + slot;
    for (; j + 4 < e0; j += 8) {
        int sA = csrc[j], sB = csrc[j + 4];
        float wA = __expf(lrelu(as2[sA] + add));
        float wB = __expf(lrelu(as2[sB] + add));
        float4 hA = *(const float4*)(hb + (size_t)sA * 64);
        float4 hB = *(const float4*)(hb + (size_t)sB * 64);
        ax = fmaf(wA, hA.x, ax); ay = fmaf(wA, hA.y, ay);
        az = fmaf(wA, hA.z, az); aw = fmaf(wA, hA.w, aw);
        den += wA;
        ax = fmaf(wB, hB.x, ax); ay = fmaf(wB, hB.y, ay);
        az = fmaf(wB, hB.z, az); aw = fmaf(wB, hB.w, aw);
        den += wB;
    }
    if (j < e0) {
        int s = csrc[j];
        float w = __expf(lrelu(as2[s] + add));
        float4 hv = *(const float4*)(hb + (size_t)s * 64);
        ax = fmaf(w, hv.x, ax); ay = fmaf(w, hv.y, ay);
        az = fmaf(w, hv.z, az); aw = fmaf(w, hv.w, aw);
        den += w;
    }
#pragma unroll
    for (int off = 16; off <= 32; off <<= 1) {
        ax += __shfl_xor(ax, off, 64); ay += __shfl_xor(ay, off, 64);
        az += __shfl_xor(az, off, 64); aw += __shfl_xor(aw, off, 64);
        den += __shfl_xor(den, off, 64);
    }
    float inv = 1.f / den;
    float4 bb = *(const float4*)(bias + sl * 4);
    float4 cw = *(const float4*)(clsW + sl * 4);
    float p = fmaxf(fmaf(ax, inv, bb.x), 0.f) * cw.x
            + fmaxf(fmaf(ay, inv, bb.y), 0.f) * cw.y
            + fmaxf(fmaf(az, inv, bb.z), 0.f) * cw.z
            + fmaxf(fmaf(aw, inv, bb.w), 0.f) * cw.w;
#pragma unroll
    for (int off = 1; off <= 8; off <<= 1) p += __shfl_xor(p, off, 64);
    if (lane == 0) out[d] = p + clsB[0];
}

extern "C" void kernel_launch(void* const* d_in, const int* in_sizes, int n_in,
                              void* d_out, int out_size, void* d_ws, size_t ws_size,
                              hipStream_t stream) {
    const float* x     = (const float*)d_in[0];
    const int*   ei    = (const int*)d_in[1];
    const float* projW = (const float*)d_in[2];
    const float* projB = (const float*)d_in[3];
    const float* W1    = (const float*)d_in[4];
    const float* as1w  = (const float*)d_in[5];
    const float* ad1w  = (const float*)d_in[6];
    const float* b1    = (const float*)d_in[7];
    const float* W2    = (const float*)d_in[8];
    const float* as2w  = (const float*)d_in[9];
    const float* ad2w  = (const float*)d_in[10];
    const float* b2    = (const float*)d_in[11];
    const float* clsW  = (const float*)d_in[12];
    const float* clsB  = (const float*)d_in[13];
    float* out = (float*)d_out;

    const int N = in_sizes[0] / F_IN;
    const int E = in_sizes[1] / 2;

    char* ws = (char*)d_ws;
    size_t off = 0;
    auto alloc = [&](size_t bytes) -> void* {
        void* p = ws + off;
        off += (bytes + 255) & ~(size_t)255;
        return p;
    };
    float* h0     = (float*)alloc((size_t)N * 64 * 4);   // reused as h2lin
    float* h1     = (float*)alloc((size_t)N * 256 * 4);
    float* as1    = (float*)alloc((size_t)N * 4 * 4);
    float* ad1    = (float*)alloc((size_t)N * 4 * 4);
    float* as2    = (float*)alloc((size_t)N * 4);
    float* ad2    = (float*)alloc((size_t)N * 4);
    int*   dc     = (int*)alloc((size_t)2 * N * 4);      // deg | cursor adjacent
    int*   deg    = dc;
    int*   cursor = dc + N;
    int*   rowptr = (int*)alloc((size_t)(N + 1) * 4);
    int*   parts  = (int*)alloc(1024 * 4);
    int*   csrc   = (int*)alloc((size_t)E * 4);
    float* wexp1  = (float*)alloc((size_t)E * 4 * 4);
    float* wt0    = (float*)alloc(64 * KP_PROJ * 4);
    float* wt2    = (float*)alloc(64 * 256 * 4);
    float* va     = (float*)alloc(512 * 4);
    float* h2lin  = h0;

    // weight transposes + va vectors + deg/cursor zeroing (one dispatch)
    const int ntr = 64 * KP_PROJ + 64 * 256 + 512 + 2 * N;
    k_trans<<<(ntr + 255) / 256, 256, 0, stream>>>(
        projW, W2, W1, as1w, ad1w, wt0, wt2, va, dc, 2 * N);

    // degree + row offsets
    k_deg<<<1024, 256, 0, stream>>>(ei, E, deg);
    int nblk = (N + 1023) / 1024;
    k_scan_part<<<nblk, 1024, 0, stream>>>(deg, rowptr, parts, N);
    k_scan_small<<<1, 64, 0, stream>>>(parts, nblk);
    k_scan_add<<<nblk, 1024, 0, stream>>>(rowptr, parts, N, E);

    // MLP in (+ fused as1/ad1 reduction) -- before scatter, which needs as1/ad1
    k_proj<<<(N + 31) / 32, 256, 0, stream>>>(x, wt0, projB, va, h0, as1, ad1, N);

    // scatter + fused layer-1 edge weights
    k_scatter<<<1024, 256, 0, stream>>>(ei, E, rowptr, cursor, as1, ad1, csrc, wexp1);

    // GAT layer 1 (h0-domain aggregation, precomputed weights, 4 dst/block)
    k_gat1f<<<(N + 3) / 4, 256, 0, stream>>>(h0, wexp1, as1, ad1, rowptr, csrc,
                                             W1, b1, h1, N);

    // GAT layer 2 + classifier (edge weights fused into k_gat2)
    k_lin2<<<(N + 31) / 32, 256, 0, stream>>>(h1, wt2, as2w, ad2w, h2lin, as2, ad2, N);
    k_gat2<<<(N + 3) / 4, 256, 0, stream>>>(h2lin, as2, ad2, rowptr, csrc, b2,
                                            clsW, clsB, out, N);
}